// Round 2
// baseline (584.388 us; speedup 1.0000x reference)
//
#include <hip/hip_runtime.h>

#define IN_DIM   8
#define IN_CAPS  1152
#define OUT_CAPS 10
#define OUT_DIM  16
#define BATCH    512
#define CSPLIT   8
#define CCHUNK   (IN_CAPS / CSPLIT)      // 144
#define CITER    (CCHUNK / 16)           // 9
#define SSZ      (BATCH * OUT_CAPS * OUT_DIM)   // 81920 floats = 327680 B

__device__ __forceinline__ float dot8(const float4* wp, float4 xa, float4 xb) {
  float4 wa = wp[0];
  float4 wb = wp[1];
  return wa.x * xa.x + wa.y * xa.y + wa.z * xa.z + wa.w * xa.w +
         wb.x * xb.x + wb.y * xb.y + wb.z * xb.z + wb.w * xb.w;
}

// sum across the 16 lanes of a d-group, pure-VALU via DPP (no ds_swizzle waits)
__device__ __forceinline__ float red16(float v) {
  v += __int_as_float(__builtin_amdgcn_mov_dpp(__float_as_int(v), 0xB1, 0xF, 0xF, true));  // quad_perm [1,0,3,2]
  v += __int_as_float(__builtin_amdgcn_mov_dpp(__float_as_int(v), 0x4E, 0xF, 0xF, true));  // quad_perm [2,3,0,1]
  v += __int_as_float(__builtin_amdgcn_mov_dpp(__float_as_int(v), 0x141, 0xF, 0xF, true)); // row_half_mirror
  v += __int_as_float(__builtin_amdgcn_mov_dpp(__float_as_int(v), 0x140, 0xF, 0xF, true)); // row_mirror
  return v;
}

// ---------------- sweep 1: s1[b,o,d] = 0.1 * sum_c u_hat[b,o,c,d] ----------
__global__ __launch_bounds__(256, 4) void sweep1_kernel(
    const float* __restrict__ x, const float* __restrict__ W,
    float* __restrict__ sOut) {
  __shared__ float xs[CCHUNK * IN_DIM];          // 4.6 KB
  __shared__ float sred[OUT_CAPS * OUT_DIM];
  const int tid   = threadIdx.x;
  const int b     = blockIdx.x >> 3;
  const int chunk = blockIdx.x & (CSPLIT - 1);
  const int grp   = tid >> 4;
  const int d     = tid & 15;

  const float4* xg  = (const float4*)(x + ((size_t)b * IN_CAPS + chunk * CCHUNK) * IN_DIM);
  float4*       xs4 = (float4*)xs;
  for (int i = tid; i < CCHUNK * IN_DIM / 4; i += 256) xs4[i] = xg[i];
  if (tid < OUT_CAPS * OUT_DIM) sred[tid] = 0.f;
  __syncthreads();

  float acc[OUT_CAPS];
  #pragma unroll
  for (int o = 0; o < OUT_CAPS; ++o) acc[o] = 0.f;
  const int cbase = chunk * CCHUNK;
  for (int ci = 0; ci < CITER; ++ci) {
    const int cl = ci * 16 + grp;
    const float4* xc = (const float4*)(xs + cl * IN_DIM);
    float4 xa = xc[0], xb = xc[1];
    const float* wbase = W + ((size_t)(cbase + cl) * OUT_DIM + d) * IN_DIM;
    #pragma unroll
    for (int o = 0; o < OUT_CAPS; ++o) {
      const float4* wp = (const float4*)(wbase + (size_t)o * (IN_CAPS * OUT_DIM * IN_DIM));
      acc[o] += dot8(wp, xa, xb);
    }
  }
  #pragma unroll
  for (int o = 0; o < OUT_CAPS; ++o) {
    float v = acc[o];
    v += __shfl_xor(v, 16);
    v += __shfl_xor(v, 32);
    if ((tid & 63) < 16) atomicAdd(&sred[o * OUT_DIM + d], v);
  }
  __syncthreads();
  if (tid < OUT_CAPS * OUT_DIM)
    atomicAdd(&sOut[(size_t)b * OUT_CAPS * OUT_DIM + tid], sred[tid] * 0.1f);
}

// ------- routed sweep: c = softmax_o(u_hat . sIn), sOut += sum_c c*u_hat ---
__global__ __launch_bounds__(256, 4) void sweepR_kernel(
    const float* __restrict__ x, const float* __restrict__ W,
    const float* __restrict__ sIn, float* __restrict__ sOut) {
  __shared__ float xs[CCHUNK * IN_DIM];
  __shared__ float sred[OUT_CAPS * OUT_DIM];
  const int tid   = threadIdx.x;
  const int b     = blockIdx.x >> 3;
  const int chunk = blockIdx.x & (CSPLIT - 1);
  const int grp   = tid >> 4;
  const int d     = tid & 15;

  const float4* xg  = (const float4*)(x + ((size_t)b * IN_CAPS + chunk * CCHUNK) * IN_DIM);
  float4*       xs4 = (float4*)xs;
  for (int i = tid; i < CCHUNK * IN_DIM / 4; i += 256) xs4[i] = xg[i];
  if (tid < OUT_CAPS * OUT_DIM) sred[tid] = 0.f;
  __syncthreads();

  float sv[OUT_CAPS];
  #pragma unroll
  for (int o = 0; o < OUT_CAPS; ++o)
    sv[o] = sIn[((size_t)b * OUT_CAPS + o) * OUT_DIM + d];

  float acc[OUT_CAPS];
  #pragma unroll
  for (int o = 0; o < OUT_CAPS; ++o) acc[o] = 0.f;

  const int cbase = chunk * CCHUNK;
  for (int ci = 0; ci < CITER; ++ci) {
    const int cl = ci * 16 + grp;
    const float4* xc = (const float4*)(xs + cl * IN_DIM);
    float4 xa = xc[0], xb = xc[1];
    const float* wbase = W + ((size_t)(cbase + cl) * OUT_DIM + d) * IN_DIM;
    float uh[OUT_CAPS], lg[OUT_CAPS];
    #pragma unroll
    for (int o = 0; o < OUT_CAPS; ++o) {
      const float4* wp = (const float4*)(wbase + (size_t)o * (IN_CAPS * OUT_DIM * IN_DIM));
      uh[o] = dot8(wp, xa, xb);
      lg[o] = red16(uh[o] * sv[o]);          // logit[o] for this c, all lanes
    }
    float m = lg[0];
    #pragma unroll
    for (int o = 1; o < OUT_CAPS; ++o) m = fmaxf(m, lg[o]);
    float sum = 0.f;
    #pragma unroll
    for (int o = 0; o < OUT_CAPS; ++o) { lg[o] = __expf(lg[o] - m); sum += lg[o]; }
    float inv = 1.f / sum;
    #pragma unroll
    for (int o = 0; o < OUT_CAPS; ++o) acc[o] += uh[o] * (lg[o] * inv);
  }
  #pragma unroll
  for (int o = 0; o < OUT_CAPS; ++o) {
    float v = acc[o];
    v += __shfl_xor(v, 16);
    v += __shfl_xor(v, 32);
    if ((tid & 63) < 16) atomicAdd(&sred[o * OUT_DIM + d], v);
  }
  __syncthreads();
  if (tid < OUT_CAPS * OUT_DIM)
    atomicAdd(&sOut[(size_t)b * OUT_CAPS * OUT_DIM + tid], sred[tid]);
}

extern "C" void kernel_launch(void* const* d_in, const int* in_sizes, int n_in,
                              void* d_out, int out_size, void* d_ws, size_t ws_size,
                              hipStream_t stream) {
  const float* x = (const float*)d_in[0];
  const float* W = (const float*)d_in[1];
  float* out = (float*)d_out;
  float* ws  = (float*)d_ws;
  const size_t SB = (size_t)SSZ * sizeof(float);   // 327680 B

  // ws = s1
  hipMemsetAsync(ws, 0, SB, stream);
  sweep1_kernel<<<BATCH * CSPLIT, 256, 0, stream>>>(x, W, ws);
  // out = s1 (preload), then K2 adds s2 -> out = s1 + s2 = s12
  hipMemcpyAsync(out, ws, SB, hipMemcpyDeviceToDevice, stream);
  sweepR_kernel<<<BATCH * CSPLIT, 256, 0, stream>>>(x, W, ws, out);
  // ws = final v (logits from s12 in out)
  hipMemsetAsync(ws, 0, SB, stream);
  sweepR_kernel<<<BATCH * CSPLIT, 256, 0, stream>>>(x, W, out, ws);
  hipMemcpyAsync(out, ws, SB, hipMemcpyDeviceToDevice, stream);
}

// Round 3
// 343.899 us; speedup vs baseline: 1.6993x; 1.6993x over previous
//
#include <hip/hip_runtime.h>

#define IN_DIM   8
#define IN_CAPS  1152
#define OUT_CAPS 10
#define OUT_DIM  16
#define BATCH    512
#define BTILE    8                         // batches per block (W amortization)
#define CSPLIT   32
#define CCHUNK   (IN_CAPS / CSPLIT)        // 36
#define CITER    (CCHUNK / 2)              // 18 (2 c's per iter via c_sub)
#define XROW     (CCHUNK * IN_DIM + 4)     // 292 floats, pad -> distinct banks per b_sub
#define OSTRIDE  ((size_t)IN_CAPS * OUT_DIM * IN_DIM)   // W stride over o = 147456
#define SSZ      (BATCH * OUT_CAPS * OUT_DIM)           // 81920 floats

__device__ __forceinline__ float dot8(const float4* wp, float4 xa, float4 xb) {
  float4 wa = wp[0];
  float4 wb = wp[1];
  return wa.x * xa.x + wa.y * xa.y + wa.z * xa.z + wa.w * xa.w +
         wb.x * xb.x + wb.y * xb.y + wb.z * xb.z + wb.w * xb.w;
}

// sum across the 16 d-lanes (pure VALU, DPP)
__device__ __forceinline__ float red16(float v) {
  v += __int_as_float(__builtin_amdgcn_mov_dpp(__float_as_int(v), 0xB1, 0xF, 0xF, true));  // quad_perm [1,0,3,2]
  v += __int_as_float(__builtin_amdgcn_mov_dpp(__float_as_int(v), 0x4E, 0xF, 0xF, true));  // quad_perm [2,3,0,1]
  v += __int_as_float(__builtin_amdgcn_mov_dpp(__float_as_int(v), 0x141, 0xF, 0xF, true)); // row_half_mirror
  v += __int_as_float(__builtin_amdgcn_mov_dpp(__float_as_int(v), 0x140, 0xF, 0xF, true)); // row_mirror
  return v;
}

// thread layout: d = tid&15 (out_dim lane), grp = tid>>4; b_sub = grp&7, c_sub = grp>>3.
// A wave's 4 lane-groups share c (different b) -> W loads coalesce to one 512B fetch.

__device__ __forceinline__ void stage_x(const float* __restrict__ x, float* xs,
                                        int bt, int chunk, int tid) {
  for (int idx = tid; idx < BTILE * CCHUNK * IN_DIM / 4; idx += 256) {
    int bb = idx / (CCHUNK * IN_DIM / 4);
    int j  = idx % (CCHUNK * IN_DIM / 4);
    const float4* src = (const float4*)(x + ((size_t)(bt * BTILE + bb) * IN_CAPS + chunk * CCHUNK) * IN_DIM);
    *(float4*)(xs + bb * XROW + j * 4) = src[j];
  }
}

__global__ __launch_bounds__(256, 4) void sweep1_kernel(
    const float* __restrict__ x, const float* __restrict__ W,
    float* __restrict__ sOut) {
  __shared__ float xs[BTILE * XROW];                 // 9.3 KB
  __shared__ float sred[16 * OUT_CAPS * OUT_DIM];    // 10 KB, per-grp partials
  const int tid   = threadIdx.x;
  const int bt    = blockIdx.x >> 5;
  const int chunk = blockIdx.x & (CSPLIT - 1);
  const int d     = tid & 15;
  const int grp   = tid >> 4;
  const int b_sub = grp & 7;
  const int c_sub = grp >> 3;

  stage_x(x, xs, bt, chunk, tid);
  __syncthreads();

  float acc[OUT_CAPS];
  #pragma unroll
  for (int o = 0; o < OUT_CAPS; ++o) acc[o] = 0.f;

  for (int ci = 0; ci < CITER; ++ci) {
    const int cl = ci * 2 + c_sub;
    const int cg = chunk * CCHUNK + cl;
    const float4* xc = (const float4*)(xs + b_sub * XROW + cl * IN_DIM);
    float4 xa = xc[0], xb = xc[1];
    const float* wbase = W + ((size_t)cg * OUT_DIM + d) * IN_DIM;
    #pragma unroll
    for (int o = 0; o < OUT_CAPS; ++o)
      acc[o] += dot8((const float4*)(wbase + o * OSTRIDE), xa, xb);
  }

  #pragma unroll
  for (int o = 0; o < OUT_CAPS; ++o)
    sred[(grp * OUT_CAPS + o) * OUT_DIM + d] = acc[o];
  __syncthreads();

  for (int idx = tid; idx < BTILE * OUT_CAPS * OUT_DIM; idx += 256) {
    int bb = idx / (OUT_CAPS * OUT_DIM);
    int od = idx % (OUT_CAPS * OUT_DIM);
    float v = sred[(bb * OUT_CAPS) * OUT_DIM + od] + sred[((bb + 8) * OUT_CAPS) * OUT_DIM + od];
    atomicAdd(&sOut[(size_t)(bt * BTILE + bb) * (OUT_CAPS * OUT_DIM) + od], v * 0.1f);
  }
}

__global__ __launch_bounds__(256, 4) void sweepR_kernel(
    const float* __restrict__ x, const float* __restrict__ W,
    const float* __restrict__ sIn, float* __restrict__ sOut) {
  __shared__ float xs[BTILE * XROW];
  __shared__ float sred[16 * OUT_CAPS * OUT_DIM];
  const int tid   = threadIdx.x;
  const int bt    = blockIdx.x >> 5;
  const int chunk = blockIdx.x & (CSPLIT - 1);
  const int d     = tid & 15;
  const int grp   = tid >> 4;
  const int b_sub = grp & 7;
  const int c_sub = grp >> 3;

  stage_x(x, xs, bt, chunk, tid);

  float sv[OUT_CAPS];
  const int bg = bt * BTILE + b_sub;
  #pragma unroll
  for (int o = 0; o < OUT_CAPS; ++o)
    sv[o] = sIn[((size_t)bg * OUT_CAPS + o) * OUT_DIM + d];

  float acc[OUT_CAPS];
  #pragma unroll
  for (int o = 0; o < OUT_CAPS; ++o) acc[o] = 0.f;
  __syncthreads();

  for (int ci = 0; ci < CITER; ++ci) {
    const int cl = ci * 2 + c_sub;
    const int cg = chunk * CCHUNK + cl;
    const float4* xc = (const float4*)(xs + b_sub * XROW + cl * IN_DIM);
    float4 xa = xc[0], xb = xc[1];
    const float* wbase = W + ((size_t)cg * OUT_DIM + d) * IN_DIM;
    float uh[OUT_CAPS], lg[OUT_CAPS];
    #pragma unroll
    for (int o = 0; o < OUT_CAPS; ++o) {
      uh[o] = dot8((const float4*)(wbase + o * OSTRIDE), xa, xb);
      lg[o] = red16(uh[o] * sv[o]);            // logit[o] for (b,c); all 16 lanes get it
    }
    float m = lg[0];
    #pragma unroll
    for (int o = 1; o < OUT_CAPS; ++o) m = fmaxf(m, lg[o]);
    float sum = 0.f;
    #pragma unroll
    for (int o = 0; o < OUT_CAPS; ++o) { lg[o] = __expf(lg[o] - m); sum += lg[o]; }
    float inv = 1.f / sum;
    #pragma unroll
    for (int o = 0; o < OUT_CAPS; ++o) acc[o] += uh[o] * (lg[o] * inv);
  }

  #pragma unroll
  for (int o = 0; o < OUT_CAPS; ++o)
    sred[(grp * OUT_CAPS + o) * OUT_DIM + d] = acc[o];
  __syncthreads();

  for (int idx = tid; idx < BTILE * OUT_CAPS * OUT_DIM; idx += 256) {
    int bb = idx / (OUT_CAPS * OUT_DIM);
    int od = idx % (OUT_CAPS * OUT_DIM);
    float v = sred[(bb * OUT_CAPS) * OUT_DIM + od] + sred[((bb + 8) * OUT_CAPS) * OUT_DIM + od];
    atomicAdd(&sOut[(size_t)(bt * BTILE + bb) * (OUT_CAPS * OUT_DIM) + od], v);
  }
}

extern "C" void kernel_launch(void* const* d_in, const int* in_sizes, int n_in,
                              void* d_out, int out_size, void* d_ws, size_t ws_size,
                              hipStream_t stream) {
  const float* x = (const float*)d_in[0];
  const float* W = (const float*)d_in[1];
  float* out = (float*)d_out;
  float* ws  = (float*)d_ws;
  const size_t SB = (size_t)SSZ * sizeof(float);
  const int GRID = (BATCH / BTILE) * CSPLIT;   // 2048

  hipMemsetAsync(ws, 0, SB, stream);
  sweep1_kernel<<<GRID, 256, 0, stream>>>(x, W, ws);              // ws = s1
  hipMemcpyAsync(out, ws, SB, hipMemcpyDeviceToDevice, stream);   // out = s1
  sweepR_kernel<<<GRID, 256, 0, stream>>>(x, W, ws, out);         // out = s1+s2
  hipMemsetAsync(ws, 0, SB, stream);
  sweepR_kernel<<<GRID, 256, 0, stream>>>(x, W, out, ws);         // ws = final v
  hipMemcpyAsync(out, ws, SB, hipMemcpyDeviceToDevice, stream);
}

// Round 7
// 201.918 us; speedup vs baseline: 2.8942x; 1.7032x over previous
//
#include <hip/hip_runtime.h>
#include <hip/hip_bf16.h>

#define IN_DIM   8
#define IN_CAPS  1152
#define OUT_CAPS 10
#define OUT_DIM  16
#define BATCH    512
#define CSPLIT   24
#define CCHUNK   (IN_CAPS / CSPLIT)     // 48 c per block
#define NT4      (CCHUNK / 4)           // 12 tile4 (4 c) per block
#define BT       16                     // batches per block (MFMA N)
#define NBT      (BATCH / BT)           // 32
#define SSZ      (BATCH * OUT_CAPS * OUT_DIM)   // 81920 f32
#define SROW     164                    // shorts per b-row in s_bf (bank-spread, 8B-aligned)
#define ACCROW   168                    // f32 per b-row in sacc
#define ACCWAVE  (16 * ACCROW)          // 2688

typedef float  f32x4 __attribute__((ext_vector_type(4)));
typedef short  s16x8 __attribute__((ext_vector_type(8)));

static __device__ __forceinline__ short f2bs(float f) {
  __hip_bfloat16 h = __float2bfloat16(f);
  short s;
  __builtin_memcpy(&s, &h, 2);
  return s;
}

// MODE 0: cw = 0.1 (softmax of zero logits), write s1 -> sOut (ws.A)
// MODE 1: logits from sA (=s1),  write s2 -> sOut (ws.B)
// MODE 2: logits from sA+sB (=s1+s2), write v -> sOut (d_out)
// NOTE: the 0.1 of MODE 0 is applied ONCE, inside z8 (cwA/cwB). No output scale.
// MFMA 16x16x32 frag k-map (two 16x16x16 halves):
//   elem j<4 : k = 4*(lane>>4)+j ; elem j>=4 : k = 16+4*(lane>>4)+(j-4)
//   A row m = lane&15 ; B col n = lane&15 ; D: col = lane&15, row = 4*(lane>>4)+reg
template<int MODE>
__global__ __launch_bounds__(256, 3) void sweep_kernel(
    const float* __restrict__ x, const float* __restrict__ W,
    const float* __restrict__ sA, const float* __restrict__ sB,
    float* __restrict__ sOut) {
  __shared__ short s_bf[16 * SROW];        // s[b][o*16+d] bf16
  __shared__ float sacc[4 * ACCWAVE];      // per-wave s_new partials

  const int tid  = threadIdx.x;
  const int wid  = tid >> 6;
  const int lane = tid & 63;
  const int b    = lane & 15;              // batch-within-tile / d / ci (role per frag)
  const int g    = lane >> 4;              // k-group
  const int bt   = blockIdx.x / CSPLIT;
  const int ch   = blockIdx.x % CSPLIT;
  const int c0   = ch * CCHUNK;
  const int bb0  = bt * BT;

  if (MODE != 0) {
    for (int k = tid; k < 16 * 160; k += 256) {
      int bb = k / 160, od = k % 160;
      float v = sA[(size_t)(bb0 + bb) * 160 + od];
      if (MODE == 2) v += sB[(size_t)(bb0 + bb) * 160 + od];
      s_bf[bb * SROW + od] = f2bs(v);
    }
  }
  for (int k = tid; k < 4 * ACCWAVE; k += 256) sacc[k] = 0.f;
  __syncthreads();

  f32x4 acc[OUT_CAPS];
  #pragma unroll
  for (int o = 0; o < OUT_CAPS; ++o) acc[o] = (f32x4){0.f, 0.f, 0.f, 0.f};

  const int isub = 4 * (g & 1);

  for (int t = wid; t < NT4; t += 4) {
    const int c4 = c0 + t * 4;
    const int cA = c4 + (g >> 1);          // this lane's c for half 0
    const int cB = c4 + 2 + (g >> 1);      // this lane's c for half 1
    const float4 xq0 = *(const float4*)(x + ((size_t)(bb0 + b) * IN_CAPS + cA) * IN_DIM + isub);
    const float4 xq1 = *(const float4*)(x + ((size_t)(bb0 + b) * IN_CAPS + cB) * IN_DIM + isub);

    float lg[2][OUT_CAPS];

    if (MODE != 0) {
      #pragma unroll
      for (int o = 0; o < OUT_CAPS; ++o) {
        // B1 frag: s[b][o][d], k=d (j<4: d=4g+j real; j>=4: zero-pad)
        ushort4 sv = *(const ushort4*)&s_bf[b * SROW + o * 16 + 4 * g];
        s16x8 sb = {(short)sv.x, (short)sv.y, (short)sv.z, (short)sv.w, 0, 0, 0, 0};
        #pragma unroll
        for (int h = 0; h < 2; ++h) {
          // A1 frag: rows m=ci=lane&15 -> c=c4+2h+(m>>3), i=m&7; k=d=4g+j
          const int cm = c4 + 2 * h + (b >> 3);
          const float* wp = W + (((size_t)o * IN_CAPS + cm) * OUT_DIM + 4 * g) * IN_DIM + (b & 7);
          s16x8 a1 = {f2bs(wp[0]), f2bs(wp[8]), f2bs(wp[16]), f2bs(wp[24]), 0, 0, 0, 0};
          f32x4 zz = (f32x4){0.f, 0.f, 0.f, 0.f};
          f32x4 d1 = __builtin_amdgcn_mfma_f32_16x16x32_bf16(a1, sb, zz, 0, 0, 0);
          // uv partial: lane's rows ci=4g+r, c = (h? cB:cA), i = isub+r
          const float4 xq = h ? xq1 : xq0;
          float p = d1[0] * xq.x + d1[1] * xq.y + d1[2] * xq.z + d1[3] * xq.w;
          p += __shfl_xor(p, 16);          // pair (g, g^1) completes sum over i=0..7
          lg[h][o] = p;
        }
      }
      // softmax over o for the lane's two c's (cA, cB)
      #pragma unroll
      for (int h = 0; h < 2; ++h) {
        float m = lg[h][0];
        #pragma unroll
        for (int o = 1; o < OUT_CAPS; ++o) m = fmaxf(m, lg[h][o]);
        float sum = 0.f;
        #pragma unroll
        for (int o = 0; o < OUT_CAPS; ++o) { lg[h][o] = __expf(lg[h][o] - m); sum += lg[h][o]; }
        float inv = 1.f / sum;
        #pragma unroll
        for (int o = 0; o < OUT_CAPS; ++o) lg[h][o] *= inv;
      }
    }

    // GEMM2: acc[o][d,b] += sum_ci W[o,ci,d] * (cw*x)[b,ci]   (K=32 = 4 c's, all real)
    #pragma unroll
    for (int o = 0; o < OUT_CAPS; ++o) {
      const float cwA = (MODE == 0) ? 0.1f : lg[0][o];
      const float cwB = (MODE == 0) ? 0.1f : lg[1][o];
      s16x8 z8 = {f2bs(cwA * xq0.x), f2bs(cwA * xq0.y), f2bs(cwA * xq0.z), f2bs(cwA * xq0.w),
                  f2bs(cwB * xq1.x), f2bs(cwB * xq1.y), f2bs(cwB * xq1.z), f2bs(cwB * xq1.w)};
      // A2 frag: m=d=lane&15; k=ci -> (cA, i=isub+j) then (cB, i=isub+j-4)
      const float4 wva = *(const float4*)(W + (((size_t)o * IN_CAPS + cA) * OUT_DIM + b) * IN_DIM + isub);
      const float4 wvb = *(const float4*)(W + (((size_t)o * IN_CAPS + cB) * OUT_DIM + b) * IN_DIM + isub);
      s16x8 a2 = {f2bs(wva.x), f2bs(wva.y), f2bs(wva.z), f2bs(wva.w),
                  f2bs(wvb.x), f2bs(wvb.y), f2bs(wvb.z), f2bs(wvb.w)};
      acc[o] = __builtin_amdgcn_mfma_f32_16x16x32_bf16(a2, z8, acc[o], 0, 0, 0);
    }
  }

  // dump acc to wave-private LDS region: lane holds s_new[b][o][d=4g+r]
  {
    float* sa = &sacc[wid * ACCWAVE + b * ACCROW];
    #pragma unroll
    for (int o = 0; o < OUT_CAPS; ++o) {
      #pragma unroll
      for (int r = 0; r < 4; ++r) sa[o * 16 + 4 * g + r] = acc[o][r];
    }
  }
  __syncthreads();

  for (int k = tid; k < 16 * 160; k += 256) {
    int bb = k / 160, od = k % 160;
    float v = sacc[0 * ACCWAVE + bb * ACCROW + od] + sacc[1 * ACCWAVE + bb * ACCROW + od] +
              sacc[2 * ACCWAVE + bb * ACCROW + od] + sacc[3 * ACCWAVE + bb * ACCROW + od];
    atomicAdd(&sOut[(size_t)(bb0 + bb) * 160 + od], v);
  }
}

extern "C" void kernel_launch(void* const* d_in, const int* in_sizes, int n_in,
                              void* d_out, int out_size, void* d_ws, size_t ws_size,
                              hipStream_t stream) {
  const float* x = (const float*)d_in[0];
  const float* W = (const float*)d_in[1];
  float* out = (float*)d_out;
  float* wsA = (float*)d_ws;              // s1
  float* wsB = wsA + SSZ;                 // s2
  const size_t SB = (size_t)SSZ * sizeof(float);
  const int GRID = NBT * CSPLIT;   // 768

  hipMemsetAsync(d_ws, 0, 2 * SB, stream);
  sweep_kernel<0><<<GRID, 256, 0, stream>>>(x, W, wsA, wsB, wsA);  // wsA = s1 (0.1 inside z8)
  sweep_kernel<1><<<GRID, 256, 0, stream>>>(x, W, wsA, wsB, wsB);  // wsB = s2
  sweep_kernel<2><<<GRID, 256, 0, stream>>>(x, W, wsA, wsB, out);  // out = v
}